// Round 2
// baseline (180.180 us; speedup 1.0000x reference)
//
#include <hip/hip_runtime.h>

#define SQH 0.70710678118654752440f

// ---------------- filter constants (fp32) ----------------
namespace dt {
constexpr float H0O[5] = {-0.05f, 0.25f, 0.5f, 0.25f, -0.05f};
constexpr float H1O[7] = {-3.f/280.f, 15.f/280.f, 73.f/280.f, -170.f/280.f,
                          73.f/280.f, 15.f/280.f, -3.f/280.f};
constexpr float H0B[10] = {0.03516384f, 0.f, -0.08832942f, 0.23389032f, 0.76027237f,
                           0.5875183f, 0.f, -0.11430184f, 0.f, 0.f};
constexpr float H0A[10] = {0.f, 0.f, -0.11430184f, 0.f, 0.5875183f,
                           0.76027237f, 0.23389032f, -0.08832942f, 0.f, 0.03516384f};
constexpr float H1A[10] = {0.03516384f, 0.f, -0.08832942f, -0.23389032f, 0.76027237f,
                           -0.5875183f, 0.f, 0.11430184f, 0.f, 0.f};
constexpr float H1B[10] = {0.f, 0.f, 0.11430184f, 0.f, -0.5875183f,
                           0.76027237f, -0.23389032f, -0.08832942f, 0.f, 0.03516384f};
}

// symmetric reflection for n=512 (single reflection; max overhang here is 10)
__device__ __forceinline__ int refl512(int i) {
  i = (i < 0) ? (-1 - i) : i;
  return (i > 511) ? (1023 - i) : i;
}

// =====================================================================
// Kernel 1: level-1 biorthogonal filters (H then W), q2c -> out_h0,
// and LL band -> ws (lolo). Tile 32x32 (x3 channels) per block.
// LDS: s_lo/s_hi 32x114 each + 4608-float union buffer (input tile /
// per-half subband staging) = 47.6 KB.
// grid = (16 wtiles, 16 htiles, 16 batch), block = 256
// =====================================================================
__global__ __launch_bounds__(256)
void k_level1(const float* __restrict__ x, float* __restrict__ lolo,
              float* __restrict__ outh0) {
  const int b   = blockIdx.z;
  const int h0  = blockIdx.y << 5;
  const int w0  = blockIdx.x << 5;
  const int tid = threadIdx.x;

  __shared__ float s_lo[32][114];   // H-lowpass, rows r, cols (cw*3+c), cw has +-3 halo
  __shared__ float s_hi[32][114];   // H-highpass
  __shared__ float s_buf[4608];     // union: input tile 38x114=4332 floats,
                                    // later 3 subbands x 16 rows x 96 = 4608 floats

  // ---- stage 0: load input tile (38 x 38 x 3) with symmetric reflect ----
  for (int idx = tid; idx < 38 * 114; idx += 256) {
    const int r  = idx / 114;
    const int q  = idx - r * 114;
    const int cw = q / 3;
    const int c  = q - cw * 3;
    const int gh = refl512(h0 - 3 + r);
    const int gw = refl512(w0 - 3 + cw);
    s_buf[idx] = x[(((b << 9) + gh) * 512 + gw) * 3 + c];
  }
  __syncthreads();

  // ---- stage 1: filter along H (rows). lo: 5-tap, hi: 7-tap ----
  for (int idx = tid; idx < 32 * 114; idx += 256) {
    const int r = idx / 114;
    const int q = idx - r * 114;
    float lo = 0.f, hi = 0.f;
#pragma unroll
    for (int k = 0; k < 5; ++k) lo += dt::H0O[k] * s_buf[(r + 5 - k) * 114 + q];
#pragma unroll
    for (int k = 0; k < 7; ++k) hi += dt::H1O[k] * s_buf[(r + 6 - k) * 114 + q];
    s_lo[r][q] = lo;
    s_hi[r][q] = hi;
  }
  __syncthreads();   // also: last read of input tile before s_buf is reused

  // ---- stage 2: filter along W; lolo -> ws, 3 subbands -> s_buf; q2c -> out_h0
  // done in 2 halves of 16 rows to keep LDS under 64 KB
  for (int half = 0; half < 2; ++half) {
    for (int idx = tid; idx < 16 * 96; idx += 256) {
      const int rr = idx / 96;
      const int q  = idx - rr * 96;
      const int r  = (half << 4) + rr;
      const int w  = q / 3;
      const int c  = q - w * 3;
      float ll = 0.f, lh = 0.f, hl = 0.f, hh = 0.f;
#pragma unroll
      for (int k = 0; k < 5; ++k) {
        const int cc = (w + 5 - k) * 3 + c;
        ll += dt::H0O[k] * s_lo[r][cc];
        hl += dt::H0O[k] * s_hi[r][cc];
      }
#pragma unroll
      for (int k = 0; k < 7; ++k) {
        const int cc = (w + 6 - k) * 3 + c;
        lh += dt::H1O[k] * s_lo[r][cc];
        hh += dt::H1O[k] * s_hi[r][cc];
      }
      lolo[(((b << 9) + (h0 + r)) * 512 + (w0 + w)) * 3 + c] = ll;
      s_buf[0 * 1536 + rr * 96 + q] = hl;   // hi_lo  -> bands 0/5
      s_buf[1 * 1536 + rr * 96 + q] = hh;   // hi_hi  -> bands 1/4
      s_buf[2 * 1536 + rr * 96 + q] = lh;   // lo_hi  -> bands 2/3
    }
    __syncthreads();

    // q2c + pack: 8 (i) x 16 (j) x 36 components, coalesced writes
    for (int o = tid; o < 8 * 16 * 36; o += 256) {
      const int band = o % 6;
      const int c    = (o / 6) % 3;
      const int ri   = (o / 18) & 1;
      const int j    = (o / 36) & 15;
      const int il   = o / 576;
      const int sb   = (band < 3) ? band : (5 - band);
      const bool sec = band >= 3;
      const int r0 = (il << 1), r1 = r0 + 1;
      float v;
      if (ri == 0) {   // re = s*(a -+ d)
        const float av = s_buf[sb * 1536 + r0 * 96 + (2 * j) * 3 + c];
        const float dv = s_buf[sb * 1536 + r1 * 96 + (2 * j + 1) * 3 + c];
        v = SQH * (sec ? (av + dv) : (av - dv));
      } else {         // im = s*(b +- c)
        const float bv = s_buf[sb * 1536 + r0 * 96 + (2 * j + 1) * 3 + c];
        const float cv = s_buf[sb * 1536 + r1 * 96 + (2 * j) * 3 + c];
        v = SQH * (sec ? (bv - cv) : (bv + cv));
      }
      const int gi = (h0 >> 1) + (half << 3) + il;
      const int gj = (w0 >> 1) + j;
      outh0[(((b << 8) + gi) * 256 + gj) * 36 + ri * 18 + c * 6 + band] = v;
    }
    __syncthreads();  // before next half overwrites s_buf
  }
}

// =====================================================================
// Kernel 2a: coldfilt along H on lolo -> lo2 (H0B/H0A) and hi2 (H1B/H1A).
// even m=2n: sum_p hEven[p]*x[ref(4n+offE-2p)], odd: hOdd[p]*x[ref(4n+offO-2p)]
// lo (sum ha*hb>0): even=(H0B,10), odd=(H0A,11)
// hi (sum ha*hb<0): even=(H1A,11), odd=(H1B,10)
// One thread per output (b,m,w,c); parity is wave-uniform.
// =====================================================================
__global__ __launch_bounds__(256)
void k_coldfilt_h(const float* __restrict__ src, float* __restrict__ lo2,
                  float* __restrict__ hi2) {
  const int idx = blockIdx.x * 256 + threadIdx.x;   // total 16*256*512*3
  const int wc  = idx % 1536;                       // w*3 + c
  const int m   = (idx / 1536) & 255;
  const int b   = idx / 393216;
  const int n   = m >> 1;
  const int base = b * 786432 + wc;                 // row stride = 1536 floats
  float alo = 0.f, ahi = 0.f;
  if ((m & 1) == 0) {
#pragma unroll
    for (int p = 0; p < 10; ++p) {
      if (dt::H0B[p] != 0.f)
        alo += dt::H0B[p] * src[base + refl512(4 * n + 10 - 2 * p) * 1536];
      if (dt::H1A[p] != 0.f)
        ahi += dt::H1A[p] * src[base + refl512(4 * n + 11 - 2 * p) * 1536];
    }
  } else {
#pragma unroll
    for (int p = 0; p < 10; ++p) {
      if (dt::H0A[p] != 0.f)
        alo += dt::H0A[p] * src[base + refl512(4 * n + 11 - 2 * p) * 1536];
      if (dt::H1B[p] != 0.f)
        ahi += dt::H1B[p] * src[base + refl512(4 * n + 10 - 2 * p) * 1536];
    }
  }
  lo2[idx] = alo;
  hi2[idx] = ahi;
}

// =====================================================================
// Kernel 2b: coldfilt along W on lo2/hi2 rows (2i, 2i+1), then
// lolo2 -> out0 and q2c -> out_h1.  One block per (b, i<128).
// LDS: 4 input rows (lo2/hi2 x 2) 24.6 KB + 3 subband rows-pairs 18.4 KB.
// =====================================================================
__global__ __launch_bounds__(256)
void k_level2b(const float* __restrict__ lo2, const float* __restrict__ hi2,
               float* __restrict__ out0, float* __restrict__ outh1) {
  const int bi = blockIdx.x;
  const int b  = bi >> 7;
  const int i  = bi & 127;
  const int tid = threadIdx.x;

  __shared__ float s_row[2][2][1536];  // [lo/hi][hp][w*3+c]
  __shared__ float s_sub[3][2][768];   // [hilo,hihi,lohi][hp][m*3+c]

  // load rows h = 2i, 2i+1 of lo2 and hi2
  // t = rowIdx*1536 + q, rowIdx = src*2 + hp   (FIXED decomposition)
  for (int t = tid; t < 6144; t += 256) {
    const int rowIdx = t / 1536;          // 0..3
    const int q      = t - rowIdx * 1536;
    const int src    = rowIdx >> 1;
    const int hp     = rowIdx & 1;
    const float* p = src ? hi2 : lo2;
    s_row[src][hp][q] = p[((b << 8) + (i << 1) + hp) * 1536 + q];
  }
  __syncthreads();

  // W-direction coldfilt: items (hp, par, mm, c); par wave-uniform
  for (int k = 0; k < 6; ++k) {
    const int it  = tid + (k << 8);
    const int hp  = it / 768;
    const int rem = it - hp * 768;
    const int par = rem / 384;
    const int t2  = rem - par * 384;
    const int mm  = t2 / 3;
    const int c   = t2 - mm * 3;
    const int m   = (mm << 1) + par;
    float ll = 0.f, lh = 0.f, hl = 0.f, hh = 0.f;
    if (par == 0) {
#pragma unroll
      for (int p = 0; p < 10; ++p) {
        if (dt::H0B[p] != 0.f) {
          const int j = refl512(4 * mm + 10 - 2 * p) * 3 + c;
          ll += dt::H0B[p] * s_row[0][hp][j];
          hl += dt::H0B[p] * s_row[1][hp][j];
        }
        if (dt::H1A[p] != 0.f) {
          const int j = refl512(4 * mm + 11 - 2 * p) * 3 + c;
          lh += dt::H1A[p] * s_row[0][hp][j];
          hh += dt::H1A[p] * s_row[1][hp][j];
        }
      }
    } else {
#pragma unroll
      for (int p = 0; p < 10; ++p) {
        if (dt::H0A[p] != 0.f) {
          const int j = refl512(4 * mm + 11 - 2 * p) * 3 + c;
          ll += dt::H0A[p] * s_row[0][hp][j];
          hl += dt::H0A[p] * s_row[1][hp][j];
        }
        if (dt::H1B[p] != 0.f) {
          const int j = refl512(4 * mm + 10 - 2 * p) * 3 + c;
          lh += dt::H1B[p] * s_row[0][hp][j];
          hh += dt::H1B[p] * s_row[1][hp][j];
        }
      }
    }
    out0[(((b << 8) + (i << 1) + hp) * 256 + m) * 3 + c] = ll;  // lolo2
    s_sub[0][hp][m * 3 + c] = hl;   // hi_lo -> bands 0/5
    s_sub[1][hp][m * 3 + c] = hh;   // hi_hi -> bands 1/4
    s_sub[2][hp][m * 3 + c] = lh;   // lo_hi -> bands 2/3
  }
  __syncthreads();

  // q2c + pack out_h1 row (b,i): 128 j x 36, layout ri*18 + band*3 + c
  const int rowbase = ((b << 7) + i) * 4608;
  for (int o = tid; o < 4608; o += 256) {
    const int c    = o % 3;
    const int band = (o / 3) % 6;
    const int ri   = (o / 18) & 1;
    const int j    = o / 36;
    const int sb   = (band < 3) ? band : (5 - band);
    const bool sec = band >= 3;
    float v;
    if (ri == 0) {
      const float av = s_sub[sb][0][(2 * j) * 3 + c];
      const float dv = s_sub[sb][1][(2 * j + 1) * 3 + c];
      v = SQH * (sec ? (av + dv) : (av - dv));
    } else {
      const float bv = s_sub[sb][0][(2 * j + 1) * 3 + c];
      const float cv = s_sub[sb][1][(2 * j) * 3 + c];
      v = SQH * (sec ? (bv - cv) : (bv + cv));
    }
    outh1[rowbase + o] = v;
  }
}

// =====================================================================
extern "C" void kernel_launch(void* const* d_in, const int* in_sizes, int n_in,
                              void* d_out, int out_size, void* d_ws, size_t ws_size,
                              hipStream_t stream) {
  const float* x = (const float*)d_in[0];
  float* out = (float*)d_out;

  // output layout (flat, fp32): lolo2 | out_h0 | out_h1
  float* out0  = out;                    // 16*256*256*3  = 3,145,728
  float* outh0 = out + 3145728;          // 16*256*256*36 = 37,748,736
  float* outh1 = out + 40894464;         // 16*128*128*36 = 9,437,184

  // workspace (fp32): lolo (12,582,912) | lo2 (6,291,456) | hi2 (6,291,456)
  // total 100,663,296 bytes
  float* lolo = (float*)d_ws;
  float* lo2  = lolo + 12582912;
  float* hi2  = lo2 + 6291456;

  k_level1<<<dim3(16, 16, 16), 256, 0, stream>>>(x, lolo, outh0);
  k_coldfilt_h<<<24576, 256, 0, stream>>>(lolo, lo2, hi2);
  k_level2b<<<2048, 256, 0, stream>>>(lo2, hi2, out0, outh1);
}

// Round 3
// 180.123 us; speedup vs baseline: 1.0003x; 1.0003x over previous
//
#include <hip/hip_runtime.h>

#define SQH 0.70710678118654752440f

// ---------------- filter constants (fp32) ----------------
namespace dt {
constexpr float H0O[5] = {-0.05f, 0.25f, 0.5f, 0.25f, -0.05f};
constexpr float H1O[7] = {-3.f/280.f, 15.f/280.f, 73.f/280.f, -170.f/280.f,
                          73.f/280.f, 15.f/280.f, -3.f/280.f};
constexpr float H0B[10] = {0.03516384f, 0.f, -0.08832942f, 0.23389032f, 0.76027237f,
                           0.5875183f, 0.f, -0.11430184f, 0.f, 0.f};
constexpr float H0A[10] = {0.f, 0.f, -0.11430184f, 0.f, 0.5875183f,
                           0.76027237f, 0.23389032f, -0.08832942f, 0.f, 0.03516384f};
constexpr float H1A[10] = {0.03516384f, 0.f, -0.08832942f, -0.23389032f, 0.76027237f,
                           -0.5875183f, 0.f, 0.11430184f, 0.f, 0.f};
constexpr float H1B[10] = {0.f, 0.f, 0.11430184f, 0.f, -0.5875183f,
                           0.76027237f, -0.23389032f, -0.08832942f, 0.f, 0.03516384f};
}

// symmetric reflection for n=512 (single reflection; max overhang here is 10)
__device__ __forceinline__ int refl512(int i) {
  i = (i < 0) ? (-1 - i) : i;
  return (i > 511) ? (1023 - i) : i;
}

// decode q2c component -> LDS read addrs (within half subband buffer) + sign
// subband buffer: s_sub[sb] plane at sb*1553, row stride 97, pair rows at +il*194
__device__ __forceinline__ void q2c_decode(int comp, int jj, int& adA, int& adB,
                                           float& sB) {
  const int band = comp % 6;
  const int cch  = (comp / 6) % 3;
  const int ri   = comp / 18;
  const int sb   = (band < 3) ? band : (5 - band);
  const bool sec = band >= 3;
  const int colA = 2 * jj + ((ri == 0) ? 0 : 1);
  const int colB = 2 * jj + ((ri == 0) ? 1 : 0);
  adA = sb * 1553 + colA * 3 + cch;
  adB = sb * 1553 + 97 + colB * 3 + cch;
  sB = (((ri == 0) != sec) ? -1.f : 1.f) * SQH;
}

// =====================================================================
// Kernel 1: level-1 filters (H then W), q2c -> out_h0, LL -> ws (lolo).
// 32x32x3 tile per block, 384 threads (6 waves).
// All inner-loop indexing is incremental (per-thread constants + row adds).
// LDS: s_lo/s_hi [32][128] + 4864-float union (s_in[38][128] / s_sub[3][1553])
//   = 52224 B -> 3 blocks/CU, 18 waves.
// =====================================================================
__global__ __launch_bounds__(384)
void k_level1(const float* __restrict__ x, float* __restrict__ lolo,
              float* __restrict__ outh0) {
  const int b  = blockIdx.z;
  const int h0 = blockIdx.y << 5;
  const int w0 = blockIdx.x << 5;
  const int t  = threadIdx.x;

  __shared__ float s_lo[32 * 128];
  __shared__ float s_hi[32 * 128];
  __shared__ float s_buf[4864];   // union: s_in[38][128]  |  s_sub[3][1553]

  // ---------- per-thread constants ----------
  const int q128 = t & 127;       // stage 0/1 column
  const int rg3  = t >> 7;        // 0..2
  int cw = q128 / 3, c0 = q128 - 3 * cw;
  if (q128 >= 114) { cw = 37; c0 = 0; }          // ghost columns: clamp (unused)
  const int gw    = refl512(w0 - 3 + cw);
  const int xcol  = gw * 3 + c0;

  const int q96 = t % 96;         // stage 2 column (w*3+c)
  const int rg4 = t / 96;         // 0..3

  int adA1, adB1, adA2, adB2; float sB1, sB2;
  q2c_decode(t % 36, t / 36, adA1, adB1, sB1);
  q2c_decode((t + 384) % 36, (t + 384) / 36, adA2, adB2, sB2);
  const int ob = ((((b << 8) + (h0 >> 1)) << 8) + (w0 >> 1)) * 36;

  const int lolo_base = ((b << 9) + h0) * 1536 + w0 * 3 + q96;

  // ---------- stage 0: load x tile rows h0-3 .. h0+34 ----------
  for (int r = rg3; r < 38; r += 3) {
    const int gh = refl512(h0 - 3 + r);
    s_buf[r * 128 + q128] = x[((b << 9) + gh) * 1536 + xcol];
  }
  __syncthreads();

  // ---------- stage 1: H filter (symmetric taps: 5->3, 7->4 FMA) ----------
  for (int r = rg3; r < 32; r += 3) {
    const float* col = s_buf + r * 128 + q128;
    const float v0 = col[0],   v1 = col[128], v2 = col[256], v3 = col[384];
    const float v4 = col[512], v5 = col[640], v6 = col[768];
    s_lo[r * 128 + q128] = dt::H0O[0] * (v1 + v5) + dt::H0O[1] * (v2 + v4)
                         + dt::H0O[2] * v3;
    s_hi[r * 128 + q128] = dt::H1O[0] * (v0 + v6) + dt::H1O[1] * (v1 + v5)
                         + dt::H1O[2] * (v2 + v4) + dt::H1O[3] * v3;
  }

  // ---------- stage 2 + q2c, two halves of 16 rows ----------
  for (int half = 0; half < 2; ++half) {
    __syncthreads();   // s_in/s_sub last reads done; s_lo/s_hi ready
    const int rbase = half << 4;
    for (int rr = rg4; rr < 16; rr += 4) {
      const int r = rbase + rr;
      const float* plo = s_lo + r * 128 + q96;
      const float* phi = s_hi + r * 128 + q96;
      const float a0 = plo[0],  a1 = plo[3],  a2 = plo[6],  a3 = plo[9];
      const float a4 = plo[12], a5 = plo[15], a6 = plo[18];
      const float b0 = phi[0],  b1 = phi[3],  b2 = phi[6],  b3 = phi[9];
      const float b4 = phi[12], b5 = phi[15], b6 = phi[18];
      const float ll = dt::H0O[0]*(a1+a5) + dt::H0O[1]*(a2+a4) + dt::H0O[2]*a3;
      const float lh = dt::H1O[0]*(a0+a6) + dt::H1O[1]*(a1+a5)
                     + dt::H1O[2]*(a2+a4) + dt::H1O[3]*a3;
      const float hl = dt::H0O[0]*(b1+b5) + dt::H0O[1]*(b2+b4) + dt::H0O[2]*b3;
      const float hh = dt::H1O[0]*(b0+b6) + dt::H1O[1]*(b1+b5)
                     + dt::H1O[2]*(b2+b4) + dt::H1O[3]*b3;
      lolo[lolo_base + r * 1536] = ll;
      s_buf[0 * 1553 + rr * 97 + q96] = hl;   // hi_lo -> bands 0/5
      s_buf[1 * 1553 + rr * 97 + q96] = hh;   // hi_hi -> bands 1/4
      s_buf[2 * 1553 + rr * 97 + q96] = lh;   // lo_hi -> bands 2/3
    }
    __syncthreads();

    // q2c + pack: 8 rows x 576 contiguous floats, coalesced
    const int obh = ob + half * 73728;
#pragma unroll
    for (int il = 0; il < 8; ++il) {
      const int o = il * 194;
      const float A1 = s_buf[adA1 + o], B1 = s_buf[adB1 + o];
      outh0[obh + il * 9216 + t] = SQH * A1 + sB1 * B1;
      if (t < 192) {
        const float A2 = s_buf[adA2 + o], B2 = s_buf[adB2 + o];
        outh0[obh + il * 9216 + t + 384] = SQH * A2 + sB2 * B2;
      }
    }
  }
}

// =====================================================================
// Kernel 2a: coldfilt along H on lolo -> lo2 (H0B/H0A) and hi2 (H1B/H1A).
// even m=2n: sum_p hEven[p]*x[ref(4n+offE-2p)], odd: hOdd[p]*x[ref(4n+offO-2p)]
// lo (sum ha*hb>0): even=(H0B,10), odd=(H0A,11)
// hi (sum ha*hb<0): even=(H1A,11), odd=(H1B,10)
// One thread per output (b,m,w,c); parity is wave-uniform.
// =====================================================================
__global__ __launch_bounds__(256)
void k_coldfilt_h(const float* __restrict__ src, float* __restrict__ lo2,
                  float* __restrict__ hi2) {
  const int idx = blockIdx.x * 256 + threadIdx.x;   // total 16*256*512*3
  const int wc  = idx % 1536;                       // w*3 + c
  const int m   = (idx / 1536) & 255;
  const int b   = idx / 393216;
  const int n   = m >> 1;
  const int base = b * 786432 + wc;                 // row stride = 1536 floats
  float alo = 0.f, ahi = 0.f;
  if ((m & 1) == 0) {
#pragma unroll
    for (int p = 0; p < 10; ++p) {
      if (dt::H0B[p] != 0.f)
        alo += dt::H0B[p] * src[base + refl512(4 * n + 10 - 2 * p) * 1536];
      if (dt::H1A[p] != 0.f)
        ahi += dt::H1A[p] * src[base + refl512(4 * n + 11 - 2 * p) * 1536];
    }
  } else {
#pragma unroll
    for (int p = 0; p < 10; ++p) {
      if (dt::H0A[p] != 0.f)
        alo += dt::H0A[p] * src[base + refl512(4 * n + 11 - 2 * p) * 1536];
      if (dt::H1B[p] != 0.f)
        ahi += dt::H1B[p] * src[base + refl512(4 * n + 10 - 2 * p) * 1536];
    }
  }
  lo2[idx] = alo;
  hi2[idx] = ahi;
}

// =====================================================================
// Kernel 2b: coldfilt along W on lo2/hi2 rows (2i, 2i+1), then
// lolo2 -> out0 and q2c -> out_h1.  One block per (b, i<128).
// =====================================================================
__global__ __launch_bounds__(256)
void k_level2b(const float* __restrict__ lo2, const float* __restrict__ hi2,
               float* __restrict__ out0, float* __restrict__ outh1) {
  const int bi = blockIdx.x;
  const int b  = bi >> 7;
  const int i  = bi & 127;
  const int tid = threadIdx.x;

  __shared__ float s_row[2][2][1536];  // [lo/hi][hp][w*3+c]
  __shared__ float s_sub[3][2][768];   // [hilo,hihi,lohi][hp][m*3+c]

  // load rows h = 2i, 2i+1 of lo2 and hi2; t = rowIdx*1536 + q
  for (int t = tid; t < 6144; t += 256) {
    const int rowIdx = t / 1536;          // 0..3
    const int q      = t - rowIdx * 1536;
    const int src    = rowIdx >> 1;
    const int hp     = rowIdx & 1;
    const float* p = src ? hi2 : lo2;
    s_row[src][hp][q] = p[((b << 8) + (i << 1) + hp) * 1536 + q];
  }
  __syncthreads();

  // W-direction coldfilt: items (hp, par, mm, c); par wave-uniform
  for (int k = 0; k < 6; ++k) {
    const int it  = tid + (k << 8);
    const int hp  = it / 768;
    const int rem = it - hp * 768;
    const int par = rem / 384;
    const int t2  = rem - par * 384;
    const int mm  = t2 / 3;
    const int c   = t2 - mm * 3;
    const int m   = (mm << 1) + par;
    float ll = 0.f, lh = 0.f, hl = 0.f, hh = 0.f;
    if (par == 0) {
#pragma unroll
      for (int p = 0; p < 10; ++p) {
        if (dt::H0B[p] != 0.f) {
          const int j = refl512(4 * mm + 10 - 2 * p) * 3 + c;
          ll += dt::H0B[p] * s_row[0][hp][j];
          hl += dt::H0B[p] * s_row[1][hp][j];
        }
        if (dt::H1A[p] != 0.f) {
          const int j = refl512(4 * mm + 11 - 2 * p) * 3 + c;
          lh += dt::H1A[p] * s_row[0][hp][j];
          hh += dt::H1A[p] * s_row[1][hp][j];
        }
      }
    } else {
#pragma unroll
      for (int p = 0; p < 10; ++p) {
        if (dt::H0A[p] != 0.f) {
          const int j = refl512(4 * mm + 11 - 2 * p) * 3 + c;
          ll += dt::H0A[p] * s_row[0][hp][j];
          hl += dt::H0A[p] * s_row[1][hp][j];
        }
        if (dt::H1B[p] != 0.f) {
          const int j = refl512(4 * mm + 10 - 2 * p) * 3 + c;
          lh += dt::H1B[p] * s_row[0][hp][j];
          hh += dt::H1B[p] * s_row[1][hp][j];
        }
      }
    }
    out0[(((b << 8) + (i << 1) + hp) * 256 + m) * 3 + c] = ll;  // lolo2
    s_sub[0][hp][m * 3 + c] = hl;   // hi_lo -> bands 0/5
    s_sub[1][hp][m * 3 + c] = hh;   // hi_hi -> bands 1/4
    s_sub[2][hp][m * 3 + c] = lh;   // lo_hi -> bands 2/3
  }
  __syncthreads();

  // q2c + pack out_h1 row (b,i): 128 j x 36, layout ri*18 + band*3 + c
  const int rowbase = ((b << 7) + i) * 4608;
  for (int o = tid; o < 4608; o += 256) {
    const int c    = o % 3;
    const int band = (o / 3) % 6;
    const int ri   = (o / 18) & 1;
    const int j    = o / 36;
    const int sb   = (band < 3) ? band : (5 - band);
    const bool sec = band >= 3;
    float v;
    if (ri == 0) {
      const float av = s_sub[sb][0][(2 * j) * 3 + c];
      const float dv = s_sub[sb][1][(2 * j + 1) * 3 + c];
      v = SQH * (sec ? (av + dv) : (av - dv));
    } else {
      const float bv = s_sub[sb][0][(2 * j + 1) * 3 + c];
      const float cv = s_sub[sb][1][(2 * j) * 3 + c];
      v = SQH * (sec ? (bv - cv) : (bv + cv));
    }
    outh1[rowbase + o] = v;
  }
}

// =====================================================================
extern "C" void kernel_launch(void* const* d_in, const int* in_sizes, int n_in,
                              void* d_out, int out_size, void* d_ws, size_t ws_size,
                              hipStream_t stream) {
  const float* x = (const float*)d_in[0];
  float* out = (float*)d_out;

  float* out0  = out;                    // 16*256*256*3
  float* outh0 = out + 3145728;          // 16*256*256*36
  float* outh1 = out + 40894464;         // 16*128*128*36

  float* lolo = (float*)d_ws;            // 12,582,912 floats
  float* lo2  = lolo + 12582912;         // 6,291,456
  float* hi2  = lo2 + 6291456;           // 6,291,456

  k_level1<<<dim3(16, 16, 16), 384, 0, stream>>>(x, lolo, outh0);
  k_coldfilt_h<<<24576, 256, 0, stream>>>(lolo, lo2, hi2);
  k_level2b<<<2048, 256, 0, stream>>>(lo2, hi2, out0, outh1);
}

// Round 5
// 167.916 us; speedup vs baseline: 1.0730x; 1.0727x over previous
//
#include <hip/hip_runtime.h>

#define SQH 0.70710678118654752440f

// ---------------- filter constants (fp32) ----------------
namespace dt {
// level-1 filter symmetric halves: unscaled (for lolo) and x sqrt(1/2) (subbands)
constexpr float H0Oh[3] = {-0.05f, 0.25f, 0.5f};
constexpr float H1Oh[4] = {-3.f/280.f, 15.f/280.f, 73.f/280.f, -170.f/280.f};
constexpr float H0Os[3] = {-0.05f*SQH, 0.25f*SQH, 0.5f*SQH};
constexpr float H1Os[4] = {(-3.f/280.f)*SQH, (15.f/280.f)*SQH,
                           (73.f/280.f)*SQH, (-170.f/280.f)*SQH};
// level-2 qshift filters
constexpr float H0B[10] = {0.03516384f, 0.f, -0.08832942f, 0.23389032f, 0.76027237f,
                           0.5875183f, 0.f, -0.11430184f, 0.f, 0.f};
constexpr float H0A[10] = {0.f, 0.f, -0.11430184f, 0.f, 0.5875183f,
                           0.76027237f, 0.23389032f, -0.08832942f, 0.f, 0.03516384f};
constexpr float H1A[10] = {0.03516384f, 0.f, -0.08832942f, -0.23389032f, 0.76027237f,
                           -0.5875183f, 0.f, 0.11430184f, 0.f, 0.f};
constexpr float H1B[10] = {0.f, 0.f, 0.11430184f, 0.f, -0.5875183f,
                           0.76027237f, -0.23389032f, -0.08832942f, 0.f, 0.03516384f};
}

// symmetric reflection for n=512 (single reflection; max overhang here is 10)
__device__ __forceinline__ int refl512(int i) {
  i = (i < 0) ? (-1 - i) : i;
  return (i > 511) ? (1023 - i) : i;
}

// =====================================================================
// Kernel 1: level-1. H-filter via register rolling window (x read from
// global/L1), W-filter + q2c fused per 2x2 quad in registers, outh0
// packed in LDS and flushed as float4. lolo written PLANAR [b][c][512][512].
// 384 threads, LDS 49.3 KB -> 3 blocks/CU. 4 barriers.
// grid = (16 wtiles, 16 htiles, 16 batch)
// =====================================================================
__global__ __launch_bounds__(384)
void k_level1(const float* __restrict__ x, float* __restrict__ lolo,
              float* __restrict__ outh0) {
  const int b  = blockIdx.z;
  const int h0 = blockIdx.y << 5;
  const int w0 = blockIdx.x << 5;
  const int t  = threadIdx.x;

  __shared__ float s_lo[3 * 1288];   // [c]: plane stride 1288, row stride 40, cols 0..37 (halo 3)
  __shared__ float s_hi[3 * 1288];
  __shared__ float s_pack[4608];     // 8 out-rows x 576 (one half-tile of outh0)

  // ---------------- H phase: rolling 7-tap window down rows ----------------
  {
    const int q = t & 127;           // column id: cw*3+c, valid < 114
    const int g = t >> 7;            // 0..2 -> row ranges 0-10, 11-21, 22-31
    if (q < 114) {
      const int cw = q / 3;
      const int c  = q - 3 * cw;
      const int gw = refl512(w0 - 3 + cw);
      const float* xc = x + (size_t)b * 786432 + gw * 3 + c;
      const int rbeg = g * 11;
      const int rcnt = (g == 2) ? 10 : 11;
      float v0 = xc[refl512(h0 + rbeg - 3) * 1536];
      float v1 = xc[refl512(h0 + rbeg - 2) * 1536];
      float v2 = xc[refl512(h0 + rbeg - 1) * 1536];
      float v3 = xc[refl512(h0 + rbeg    ) * 1536];
      float v4 = xc[refl512(h0 + rbeg + 1) * 1536];
      float v5 = xc[refl512(h0 + rbeg + 2) * 1536];
      float* plo = s_lo + c * 1288 + rbeg * 40 + cw;
      float* phi = s_hi + c * 1288 + rbeg * 40 + cw;
      for (int rr = 0; rr < rcnt; ++rr) {
        const float v6 = xc[refl512(h0 + rbeg + rr + 3) * 1536];
        plo[rr * 40] = dt::H0Oh[0]*(v1+v5) + dt::H0Oh[1]*(v2+v4) + dt::H0Oh[2]*v3;
        phi[rr * 40] = dt::H1Oh[0]*(v0+v6) + dt::H1Oh[1]*(v1+v5)
                     + dt::H1Oh[2]*(v2+v4) + dt::H1Oh[3]*v3;
        v0=v1; v1=v2; v2=v3; v3=v4; v4=v5; v5=v6;
      }
    }
  }

  // quad decode (bijection t -> rp0*48 + jq*3 + c)
  const int c   = t % 3;
  const int jq  = (t / 3) & 15;
  const int rp0 = t / 48;                 // 0..7
  const int lobase = c * 1288 + 2 * jq;

  for (int half = 0; half < 2; ++half) {
    __syncthreads();   // H-writes visible (half 0) / pack flushed (half 1)

    // ------------- quad phase: 2x2 spatial, one channel -------------
    const int rp = rp0 + (half << 3);     // global row-pair 0..15
    const int r0 = rp << 1;
    float L0[10], L1[10], G0[10], G1[10];
    {
      const float2* a = (const float2*)(s_lo + lobase + r0 * 40);
      const float2* bq = (const float2*)(s_lo + lobase + r0 * 40 + 40);
      const float2* d = (const float2*)(s_hi + lobase + r0 * 40);
      const float2* e = (const float2*)(s_hi + lobase + r0 * 40 + 40);
#pragma unroll
      for (int u = 0; u < 5; ++u) {
        float2 va = a[u];  L0[2*u] = va.x; L0[2*u+1] = va.y;
        float2 vb = bq[u]; L1[2*u] = vb.x; L1[2*u+1] = vb.y;
        float2 vd = d[u];  G0[2*u] = vd.x; G0[2*u+1] = vd.y;
        float2 ve = e[u];  G1[2*u] = ve.x; G1[2*u+1] = ve.y;
      }
    }
    // W-filters. cols: we = 2jq (window idx 0 base), wo = 2jq+1 (idx +1)
    // ll (unscaled), lh/hl/hh (scaled by SQH)
    const float ll00 = dt::H0Oh[0]*(L0[1]+L0[5]) + dt::H0Oh[1]*(L0[2]+L0[4]) + dt::H0Oh[2]*L0[3];
    const float ll01 = dt::H0Oh[0]*(L0[2]+L0[6]) + dt::H0Oh[1]*(L0[3]+L0[5]) + dt::H0Oh[2]*L0[4];
    const float ll10 = dt::H0Oh[0]*(L1[1]+L1[5]) + dt::H0Oh[1]*(L1[2]+L1[4]) + dt::H0Oh[2]*L1[3];
    const float ll11 = dt::H0Oh[0]*(L1[2]+L1[6]) + dt::H0Oh[1]*(L1[3]+L1[5]) + dt::H0Oh[2]*L1[4];

    const float lh00 = dt::H1Os[0]*(L0[0]+L0[6]) + dt::H1Os[1]*(L0[1]+L0[5]) + dt::H1Os[2]*(L0[2]+L0[4]) + dt::H1Os[3]*L0[3];
    const float lh01 = dt::H1Os[0]*(L0[1]+L0[7]) + dt::H1Os[1]*(L0[2]+L0[6]) + dt::H1Os[2]*(L0[3]+L0[5]) + dt::H1Os[3]*L0[4];
    const float lh10 = dt::H1Os[0]*(L1[0]+L1[6]) + dt::H1Os[1]*(L1[1]+L1[5]) + dt::H1Os[2]*(L1[2]+L1[4]) + dt::H1Os[3]*L1[3];
    const float lh11 = dt::H1Os[0]*(L1[1]+L1[7]) + dt::H1Os[1]*(L1[2]+L1[6]) + dt::H1Os[2]*(L1[3]+L1[5]) + dt::H1Os[3]*L1[4];

    const float hl00 = dt::H0Os[0]*(G0[1]+G0[5]) + dt::H0Os[1]*(G0[2]+G0[4]) + dt::H0Os[2]*G0[3];
    const float hl01 = dt::H0Os[0]*(G0[2]+G0[6]) + dt::H0Os[1]*(G0[3]+G0[5]) + dt::H0Os[2]*G0[4];
    const float hl10 = dt::H0Os[0]*(G1[1]+G1[5]) + dt::H0Os[1]*(G1[2]+G1[4]) + dt::H0Os[2]*G1[3];
    const float hl11 = dt::H0Os[0]*(G1[2]+G1[6]) + dt::H0Os[1]*(G1[3]+G1[5]) + dt::H0Os[2]*G1[4];

    const float hh00 = dt::H1Os[0]*(G0[0]+G0[6]) + dt::H1Os[1]*(G0[1]+G0[5]) + dt::H1Os[2]*(G0[2]+G0[4]) + dt::H1Os[3]*G0[3];
    const float hh01 = dt::H1Os[0]*(G0[1]+G0[7]) + dt::H1Os[1]*(G0[2]+G0[6]) + dt::H1Os[2]*(G0[3]+G0[5]) + dt::H1Os[3]*G0[4];
    const float hh10 = dt::H1Os[0]*(G1[0]+G1[6]) + dt::H1Os[1]*(G1[1]+G1[5]) + dt::H1Os[2]*(G1[2]+G1[4]) + dt::H1Os[3]*G1[3];
    const float hh11 = dt::H1Os[0]*(G1[1]+G1[7]) + dt::H1Os[1]*(G1[2]+G1[6]) + dt::H1Os[2]*(G1[3]+G1[5]) + dt::H1Os[3]*G1[4];

    // lolo planar store (float2 per row)
    {
      float* lp = lolo + (((size_t)(b * 3 + c) * 512) + (h0 + r0)) * 512 + w0 + 2 * jq;
      *(float2*)lp = make_float2(ll00, ll01);
      *(float2*)(lp + 512) = make_float2(ll10, ll11);
    }

    // q2c in registers: a=(r0,we) b=(r0,wo) c=(r1,we) d=(r1,wo)
    // first band f: re=a-d, im=b+c ; second band 5-f: re=a+d, im=b-c
    {
      float* pk = s_pack + rp0 * 576 + jq * 36 + c * 6;
      pk[0]  = hl00 - hl11;  pk[18] = hl01 + hl10;   // band 0 (hi_lo first)
      pk[5]  = hl00 + hl11;  pk[23] = hl01 - hl10;   // band 5
      pk[1]  = hh00 - hh11;  pk[19] = hh01 + hh10;   // band 1 (hi_hi first)
      pk[4]  = hh00 + hh11;  pk[22] = hh01 - hh10;   // band 4
      pk[2]  = lh00 - lh11;  pk[20] = lh01 + lh10;   // band 2 (lo_hi first)
      pk[3]  = lh00 + lh11;  pk[21] = lh01 - lh10;   // band 3
    }
    __syncthreads();

    // ------------- flush: 8 rows x 576 floats, float4 coalesced -------------
    {
      const int gi0 = (h0 >> 1) + (half << 3);
      float4* gout = (float4*)(outh0 + ((((size_t)b << 8) + gi0) << 8) * 36
                               + (size_t)(w0 >> 1) * 36);
      const float4* sp = (const float4*)s_pack;
#pragma unroll
      for (int k = 0; k < 3; ++k) {
        const int item = t + k * 384;      // 0..1151
        const int row  = item / 144;
        const int f4   = item - row * 144;
        gout[(size_t)row * 2304 + f4] = sp[item];
      }
    }
  }
}

// =====================================================================
// Kernel 2a: coldfilt along H on planar lolo -> planar lo2/hi2.
// even m=2n: sum_p hE[p]*x[ref(4n+10-2p)], odd: hO[p]*x[ref(4n+11-2p)]
// lo: even=(H0B,10) odd=(H0A,11); hi: even=(H1A,11) odd=(H1B,10)
// One thread per (plane, m, w-pair); float2 IO. Parity wave-uniform.
// =====================================================================
__global__ __launch_bounds__(256)
void k_coldfilt_h(const float* __restrict__ src, float* __restrict__ lo2,
                  float* __restrict__ hi2) {
  const int idx = blockIdx.x * 256 + threadIdx.x;   // 48*256*256
  const int w2 = idx & 255;
  const int m  = (idx >> 8) & 255;
  const int p  = idx >> 16;                         // plane = b*3+c
  const int n  = m >> 1;
  const float2* s = (const float2*)src + (size_t)p * 131072 + w2;  // row stride 256 f2
  float2 alo = make_float2(0.f, 0.f), ahi = make_float2(0.f, 0.f);
  if (!(m & 1)) {
#pragma unroll
    for (int q = 0; q < 10; ++q) {
      if (dt::H0B[q] != 0.f) {
        const float2 v = s[(size_t)refl512(4*n + 10 - 2*q) * 256];
        alo.x += dt::H0B[q] * v.x; alo.y += dt::H0B[q] * v.y;
      }
      if (dt::H1A[q] != 0.f) {
        const float2 v = s[(size_t)refl512(4*n + 11 - 2*q) * 256];
        ahi.x += dt::H1A[q] * v.x; ahi.y += dt::H1A[q] * v.y;
      }
    }
  } else {
#pragma unroll
    for (int q = 0; q < 10; ++q) {
      if (dt::H0A[q] != 0.f) {
        const float2 v = s[(size_t)refl512(4*n + 11 - 2*q) * 256];
        alo.x += dt::H0A[q] * v.x; alo.y += dt::H0A[q] * v.y;
      }
      if (dt::H1B[q] != 0.f) {
        const float2 v = s[(size_t)refl512(4*n + 10 - 2*q) * 256];
        ahi.x += dt::H1B[q] * v.x; ahi.y += dt::H1B[q] * v.y;
      }
    }
  }
  const size_t o = (size_t)p * 65536 + (m << 8) + w2;   // planar [p][256][512] in f2
  ((float2*)lo2)[o] = alo;
  ((float2*)hi2)[o] = ahi;
}

// =====================================================================
// Kernel 2b: coldfilt along W on planar lo2/hi2 rows (2i, 2i+1), then
// lolo2 -> out0 (interleaved) and q2c -> out_h1. One block per (b, i<128).
// LDS rows stored PARITY-SPLIT (taps are single-parity -> stride-2 reads,
// no 8-way conflicts), with reflected halos. 43.8 KB -> 3 blocks/CU.
// Tap addressing: E[u+4]=x[2u], O[u+4]=x[2u+1]; tap q of output mm reads
// index (2mm+9-q) in BOTH planes (u = 2mm+5-q), u range -4..259.
// =====================================================================
__global__ __launch_bounds__(256)
void k_level2b(const float* __restrict__ lo2, const float* __restrict__ hi2,
               float* __restrict__ out0, float* __restrict__ outh1) {
  const int bi = blockIdx.x;
  const int b  = bi >> 7;
  const int i  = bi & 127;
  const int tid = threadIdx.x;

  __shared__ float s_row[2][2][2][3][264]; // [lo/hi][hp][par][c][u+4], u=w>>1
  __shared__ float s_sub[3][2][768];       // [sb][hp][c*256 + m]

  // main body: 12 rows x 512 floats as float4, parity-split into E/O planes
  for (int k = 0; k < 6; ++k) {
    const int t4 = tid + (k << 8);         // 0..1535
    const int plane = t4 >> 7;             // 0..11
    const int f4i = t4 & 127;
    const int srcn = plane / 6;
    const int rem = plane - 6 * srcn;
    const int hp = rem / 3;
    const int cc = rem - 3 * hp;
    const float4 v = *((const float4*)((srcn ? hi2 : lo2)
                       + (((size_t)(b * 3 + cc) * 256) + (i << 1) + hp) * 512) + f4i);
    *(float2*)&s_row[srcn][hp][0][cc][2 * f4i + 4] = make_float2(v.x, v.z);
    *(float2*)&s_row[srcn][hp][1][cc][2 * f4i + 4] = make_float2(v.y, v.w);
  }
  // halos: BOTH parities need u = -4..-1 and 256..259 (8 slots each)
  if (tid < 192) {
    const int pl = tid >> 4;               // 0..11
    const int s  = tid & 15;
    const int srcn = pl / 6;
    const int rem = pl - 6 * srcn;
    const int hp = rem / 3;
    const int cc = rem - 3 * hp;
    const float* grow = (srcn ? hi2 : lo2)
                        + (((size_t)(b * 3 + cc) * 256) + (i << 1) + hp) * 512;
    const int par = s >> 3;
    const int s3  = s & 7;
    const int u   = (s3 < 4) ? (s3 - 4) : (252 + s3);
    s_row[srcn][hp][par][cc][u + 4] = grow[refl512(2 * u + par)];
  }
  __syncthreads();

  // W-coldfilt: 1536 outputs = (hp, par, c, mm); par wave-uniform
  for (int k = 0; k < 6; ++k) {
    const int it  = tid + (k << 8);
    const int mm  = it & 127;
    const int cc  = (it >> 7) % 3;
    const int par = (it / 384) & 1;
    const int hp  = it / 768;
    const float* ELo = &s_row[0][hp][0][cc][2 * mm + 9];   // tap q -> [-q]
    const float* OLo = &s_row[0][hp][1][cc][2 * mm + 9];
    const float* EHi = &s_row[1][hp][0][cc][2 * mm + 9];
    const float* OHi = &s_row[1][hp][1][cc][2 * mm + 9];
    float ll = 0.f, lh = 0.f, hl = 0.f, hh = 0.f;
    if (par == 0) {   // even m: lo-filter on E (off 10), hi-filter on O (off 11)
#pragma unroll
      for (int q = 0; q < 10; ++q) {
        if (dt::H0B[q] != 0.f) { ll += dt::H0B[q] * ELo[-q]; hl += dt::H0B[q] * EHi[-q]; }
        if (dt::H1A[q] != 0.f) { lh += dt::H1A[q] * OLo[-q]; hh += dt::H1A[q] * OHi[-q]; }
      }
    } else {          // odd m: lo-filter on O (off 11), hi-filter on E (off 10)
#pragma unroll
      for (int q = 0; q < 10; ++q) {
        if (dt::H0A[q] != 0.f) { ll += dt::H0A[q] * OLo[-q]; hl += dt::H0A[q] * OHi[-q]; }
        if (dt::H1B[q] != 0.f) { lh += dt::H1B[q] * ELo[-q]; hh += dt::H1B[q] * EHi[-q]; }
      }
    }
    const int m = (mm << 1) + par;
    out0[(((size_t)(b << 8) + (i << 1) + hp) * 256 + m) * 3 + cc] = ll;  // lolo2
    s_sub[0][hp][cc * 256 + m] = hl;   // hi_lo -> bands 0/5
    s_sub[1][hp][cc * 256 + m] = hh;   // hi_hi -> bands 1/4
    s_sub[2][hp][cc * 256 + m] = lh;   // lo_hi -> bands 2/3
  }
  __syncthreads();

  // q2c + pack out_h1 row (b,i): 128 j x 36, layout ri*18 + band*3 + c
  const size_t rowbase = ((size_t)(b << 7) + i) * 4608;
  for (int o = tid; o < 4608; o += 256) {
    const int cc   = o % 3;
    const int band = (o / 3) % 6;
    const int ri   = (o / 18) & 1;
    const int j    = o / 36;
    const int sb   = (band < 3) ? band : (5 - band);
    const bool sec = band >= 3;
    float v;
    if (ri == 0) {
      const float av = s_sub[sb][0][cc * 256 + 2 * j];
      const float dv = s_sub[sb][1][cc * 256 + 2 * j + 1];
      v = SQH * (sec ? (av + dv) : (av - dv));
    } else {
      const float bv = s_sub[sb][0][cc * 256 + 2 * j + 1];
      const float cv = s_sub[sb][1][cc * 256 + 2 * j];
      v = SQH * (sec ? (bv - cv) : (bv + cv));
    }
    outh1[rowbase + o] = v;
  }
}

// =====================================================================
extern "C" void kernel_launch(void* const* d_in, const int* in_sizes, int n_in,
                              void* d_out, int out_size, void* d_ws, size_t ws_size,
                              hipStream_t stream) {
  const float* x = (const float*)d_in[0];
  float* out = (float*)d_out;

  float* out0  = out;                    // 16*256*256*3
  float* outh0 = out + 3145728;          // 16*256*256*36
  float* outh1 = out + 40894464;         // 16*128*128*36

  float* lolo = (float*)d_ws;            // planar [b][c][512][512]
  float* lo2  = lolo + 12582912;         // planar [b][c][256][512]
  float* hi2  = lo2 + 6291456;           // planar [b][c][256][512]

  k_level1<<<dim3(16, 16, 16), 384, 0, stream>>>(x, lolo, outh0);
  k_coldfilt_h<<<12288, 256, 0, stream>>>(lolo, lo2, hi2);
  k_level2b<<<2048, 256, 0, stream>>>(lo2, hi2, out0, outh1);
}

// Round 6
// 130.171 us; speedup vs baseline: 1.3842x; 1.2900x over previous
//
#include <hip/hip_runtime.h>

#define SQH 0.70710678118654752440f

// ---------------- filter constants (fp32) ----------------
namespace dt {
// level-1 filter symmetric halves: unscaled (for lolo) and x sqrt(1/2) (subbands)
constexpr float H0Oh[3] = {-0.05f, 0.25f, 0.5f};
constexpr float H1Oh[4] = {-3.f/280.f, 15.f/280.f, 73.f/280.f, -170.f/280.f};
constexpr float H0Os[3] = {-0.05f*SQH, 0.25f*SQH, 0.5f*SQH};
constexpr float H1Os[4] = {(-3.f/280.f)*SQH, (15.f/280.f)*SQH,
                           (73.f/280.f)*SQH, (-170.f/280.f)*SQH};
// level-2 qshift filters
constexpr float H0B[10] = {0.03516384f, 0.f, -0.08832942f, 0.23389032f, 0.76027237f,
                           0.5875183f, 0.f, -0.11430184f, 0.f, 0.f};
constexpr float H0A[10] = {0.f, 0.f, -0.11430184f, 0.f, 0.5875183f,
                           0.76027237f, 0.23389032f, -0.08832942f, 0.f, 0.03516384f};
constexpr float H1A[10] = {0.03516384f, 0.f, -0.08832942f, -0.23389032f, 0.76027237f,
                           -0.5875183f, 0.f, 0.11430184f, 0.f, 0.f};
constexpr float H1B[10] = {0.f, 0.f, 0.11430184f, 0.f, -0.5875183f,
                           0.76027237f, -0.23389032f, -0.08832942f, 0.f, 0.03516384f};
}

// symmetric reflection for n=512 (single reflection; max overhang here is 10)
__device__ __forceinline__ int refl512(int i) {
  i = (i < 0) ? (-1 - i) : i;
  return (i > 511) ? (1023 - i) : i;
}

// =====================================================================
// Kernel 1: level-1. H-filter: each thread owns a column, loads its 17
// source rows FULLY UNROLLED into registers (all loads in flight at
// once), then computes 11 filter rows. W-filter + q2c fused per 2x2
// quad in registers; outh0 packed in LDS, flushed as float4.
// lolo written PLANAR [b][c][512][512].
// 384 threads; LDS: s_lo/s_hi 3 planes x 33 rows x 40 (halo+pad) +
// pack 4608 = 50.1 KB -> 3 blocks/CU. 4 barriers.
// grid = (16 wtiles, 16 htiles, 16 batch)
// =====================================================================
__global__ __launch_bounds__(384)
void k_level1(const float* __restrict__ x, float* __restrict__ lolo,
              float* __restrict__ outh0) {
  const int b  = blockIdx.z;
  const int h0 = blockIdx.y << 5;
  const int w0 = blockIdx.x << 5;
  const int t  = threadIdx.x;

  __shared__ float s_lo[3 * 1320];   // [c]: plane 1320 = 33 rows x 40 (row 32 = pad)
  __shared__ float s_hi[3 * 1320];
  __shared__ float s_pack[4608];     // 8 out-rows x 576 (one half-tile of outh0)

  // ---------------- H phase: 17 loads up-front, then 11 rows ----------------
  {
    const int q = t & 127;           // column id: cw*3+c, valid < 114
    const int g = t >> 7;            // 0..2 -> row blocks 0-10, 11-21, 22-32(pad)
    if (q < 114) {
      const int cw = q / 3;
      const int c  = q - 3 * cw;
      const int gw = refl512(w0 - 3 + cw);
      const float* xc = x + (size_t)b * 786432 + gw * 3 + c;
      const int rbeg = g * 11;
      float v[17];
#pragma unroll
      for (int rr = 0; rr < 17; ++rr)
        v[rr] = xc[refl512(h0 + rbeg - 3 + rr) * 1536];
      float* plo = s_lo + c * 1320 + rbeg * 40 + cw;
      float* phi = s_hi + c * 1320 + rbeg * 40 + cw;
#pragma unroll
      for (int rr = 0; rr < 11; ++rr) {   // g=2: row 32 lands in pad row, unread
        plo[rr * 40] = dt::H0Oh[0]*(v[rr+1]+v[rr+5]) + dt::H0Oh[1]*(v[rr+2]+v[rr+4])
                     + dt::H0Oh[2]*v[rr+3];
        phi[rr * 40] = dt::H1Oh[0]*(v[rr]+v[rr+6]) + dt::H1Oh[1]*(v[rr+1]+v[rr+5])
                     + dt::H1Oh[2]*(v[rr+2]+v[rr+4]) + dt::H1Oh[3]*v[rr+3];
      }
    }
  }

  // quad decode (bijection t -> rp0*48 + jq*3 + c)
  const int c   = t % 3;
  const int jq  = (t / 3) & 15;
  const int rp0 = t / 48;                 // 0..7
  const int lobase = c * 1320 + 2 * jq;

  for (int half = 0; half < 2; ++half) {
    __syncthreads();   // H-writes visible (half 0) / pack flushed (half 1)

    // ------------- quad phase: 2x2 spatial, one channel -------------
    const int rp = rp0 + (half << 3);     // global row-pair 0..15
    const int r0 = rp << 1;
    float L0[10], L1[10], G0[10], G1[10];
    {
      const float2* a = (const float2*)(s_lo + lobase + r0 * 40);
      const float2* bq = (const float2*)(s_lo + lobase + r0 * 40 + 40);
      const float2* d = (const float2*)(s_hi + lobase + r0 * 40);
      const float2* e = (const float2*)(s_hi + lobase + r0 * 40 + 40);
#pragma unroll
      for (int u = 0; u < 5; ++u) {
        float2 va = a[u];  L0[2*u] = va.x; L0[2*u+1] = va.y;
        float2 vb = bq[u]; L1[2*u] = vb.x; L1[2*u+1] = vb.y;
        float2 vd = d[u];  G0[2*u] = vd.x; G0[2*u+1] = vd.y;
        float2 ve = e[u];  G1[2*u] = ve.x; G1[2*u+1] = ve.y;
      }
    }
    // W-filters. cols: we = 2jq (window idx 0 base), wo = 2jq+1 (idx +1)
    // ll (unscaled), lh/hl/hh (scaled by SQH)
    const float ll00 = dt::H0Oh[0]*(L0[1]+L0[5]) + dt::H0Oh[1]*(L0[2]+L0[4]) + dt::H0Oh[2]*L0[3];
    const float ll01 = dt::H0Oh[0]*(L0[2]+L0[6]) + dt::H0Oh[1]*(L0[3]+L0[5]) + dt::H0Oh[2]*L0[4];
    const float ll10 = dt::H0Oh[0]*(L1[1]+L1[5]) + dt::H0Oh[1]*(L1[2]+L1[4]) + dt::H0Oh[2]*L1[3];
    const float ll11 = dt::H0Oh[0]*(L1[2]+L1[6]) + dt::H0Oh[1]*(L1[3]+L1[5]) + dt::H0Oh[2]*L1[4];

    const float lh00 = dt::H1Os[0]*(L0[0]+L0[6]) + dt::H1Os[1]*(L0[1]+L0[5]) + dt::H1Os[2]*(L0[2]+L0[4]) + dt::H1Os[3]*L0[3];
    const float lh01 = dt::H1Os[0]*(L0[1]+L0[7]) + dt::H1Os[1]*(L0[2]+L0[6]) + dt::H1Os[2]*(L0[3]+L0[5]) + dt::H1Os[3]*L0[4];
    const float lh10 = dt::H1Os[0]*(L1[0]+L1[6]) + dt::H1Os[1]*(L1[1]+L1[5]) + dt::H1Os[2]*(L1[2]+L1[4]) + dt::H1Os[3]*L1[3];
    const float lh11 = dt::H1Os[0]*(L1[1]+L1[7]) + dt::H1Os[1]*(L1[2]+L1[6]) + dt::H1Os[2]*(L1[3]+L1[5]) + dt::H1Os[3]*L1[4];

    const float hl00 = dt::H0Os[0]*(G0[1]+G0[5]) + dt::H0Os[1]*(G0[2]+G0[4]) + dt::H0Os[2]*G0[3];
    const float hl01 = dt::H0Os[0]*(G0[2]+G0[6]) + dt::H0Os[1]*(G0[3]+G0[5]) + dt::H0Os[2]*G0[4];
    const float hl10 = dt::H0Os[0]*(G1[1]+G1[5]) + dt::H0Os[1]*(G1[2]+G1[4]) + dt::H0Os[2]*G1[3];
    const float hl11 = dt::H0Os[0]*(G1[2]+G1[6]) + dt::H0Os[1]*(G1[3]+G1[5]) + dt::H0Os[2]*G1[4];

    const float hh00 = dt::H1Os[0]*(G0[0]+G0[6]) + dt::H1Os[1]*(G0[1]+G0[5]) + dt::H1Os[2]*(G0[2]+G0[4]) + dt::H1Os[3]*G0[3];
    const float hh01 = dt::H1Os[0]*(G0[1]+G0[7]) + dt::H1Os[1]*(G0[2]+G0[6]) + dt::H1Os[2]*(G0[3]+G0[5]) + dt::H1Os[3]*G0[4];
    const float hh10 = dt::H1Os[0]*(G1[0]+G1[6]) + dt::H1Os[1]*(G1[1]+G1[5]) + dt::H1Os[2]*(G1[2]+G1[4]) + dt::H1Os[3]*G1[3];
    const float hh11 = dt::H1Os[0]*(G1[1]+G1[7]) + dt::H1Os[1]*(G1[2]+G1[6]) + dt::H1Os[2]*(G1[3]+G1[5]) + dt::H1Os[3]*G1[4];

    // lolo planar store (float2 per row)
    {
      float* lp = lolo + (((size_t)(b * 3 + c) * 512) + (h0 + r0)) * 512 + w0 + 2 * jq;
      *(float2*)lp = make_float2(ll00, ll01);
      *(float2*)(lp + 512) = make_float2(ll10, ll11);
    }

    // q2c in registers: a=(r0,we) b=(r0,wo) c=(r1,we) d=(r1,wo)
    // first band f: re=a-d, im=b+c ; second band 5-f: re=a+d, im=b-c
    {
      float* pk = s_pack + rp0 * 576 + jq * 36 + c * 6;
      pk[0]  = hl00 - hl11;  pk[18] = hl01 + hl10;   // band 0 (hi_lo first)
      pk[5]  = hl00 + hl11;  pk[23] = hl01 - hl10;   // band 5
      pk[1]  = hh00 - hh11;  pk[19] = hh01 + hh10;   // band 1 (hi_hi first)
      pk[4]  = hh00 + hh11;  pk[22] = hh01 - hh10;   // band 4
      pk[2]  = lh00 - lh11;  pk[20] = lh01 + lh10;   // band 2 (lo_hi first)
      pk[3]  = lh00 + lh11;  pk[21] = lh01 - lh10;   // band 3
    }
    __syncthreads();

    // ------------- flush: 8 rows x 576 floats, float4 coalesced -------------
    {
      const int gi0 = (h0 >> 1) + (half << 3);
      float4* gout = (float4*)(outh0 + ((((size_t)b << 8) + gi0) << 8) * 36
                               + (size_t)(w0 >> 1) * 36);
      const float4* sp = (const float4*)s_pack;
#pragma unroll
      for (int k = 0; k < 3; ++k) {
        const int item = t + k * 384;      // 0..1151
        const int row  = item / 144;
        const int f4   = item - row * 144;
        gout[(size_t)row * 2304 + f4] = sp[item];
      }
    }
  }
}

// =====================================================================
// Kernel 2a: coldfilt along H on planar lolo -> planar lo2/hi2.
// even m=2n: sum_p hE[p]*x[ref(4n+10-2p)], odd: hO[p]*x[ref(4n+11-2p)]
// lo: even=(H0B,10) odd=(H0A,11); hi: even=(H1A,11) odd=(H1B,10)
// One thread per (plane, m, w-quad); float4 IO. Parity wave-uniform.
// =====================================================================
__global__ __launch_bounds__(256)
void k_coldfilt_h(const float* __restrict__ src, float* __restrict__ lo2,
                  float* __restrict__ hi2) {
  const int idx = blockIdx.x * 256 + threadIdx.x;   // 48*256*128
  const int w4 = idx & 127;
  const int m  = (idx >> 7) & 255;
  const int p  = idx >> 15;                         // plane = b*3+c
  const int n  = m >> 1;
  const float4* s = (const float4*)src + (size_t)p * 65536 + w4;  // row stride 128 f4
  float4 alo = make_float4(0.f, 0.f, 0.f, 0.f);
  float4 ahi = make_float4(0.f, 0.f, 0.f, 0.f);
#define ACC4(acc, h, row)                                            \
  { const float4 v = s[(size_t)(row) * 128];                         \
    acc.x += (h) * v.x; acc.y += (h) * v.y;                          \
    acc.z += (h) * v.z; acc.w += (h) * v.w; }
  if (!(m & 1)) {
#pragma unroll
    for (int q = 0; q < 10; ++q) {
      if (dt::H0B[q] != 0.f) ACC4(alo, dt::H0B[q], refl512(4*n + 10 - 2*q));
      if (dt::H1A[q] != 0.f) ACC4(ahi, dt::H1A[q], refl512(4*n + 11 - 2*q));
    }
  } else {
#pragma unroll
    for (int q = 0; q < 10; ++q) {
      if (dt::H0A[q] != 0.f) ACC4(alo, dt::H0A[q], refl512(4*n + 11 - 2*q));
      if (dt::H1B[q] != 0.f) ACC4(ahi, dt::H1B[q], refl512(4*n + 10 - 2*q));
    }
  }
#undef ACC4
  const size_t o = (size_t)p * 32768 + (m << 7) + w4;   // planar [p][256][512] in f4
  ((float4*)lo2)[o] = alo;
  ((float4*)hi2)[o] = ahi;
}

// =====================================================================
// Kernel 2b: coldfilt along W on planar lo2/hi2 rows (2i, 2i+1), then
// lolo2 -> out0 (interleaved) and q2c -> out_h1. One block per (b, i<128).
// LDS rows stored PARITY-SPLIT (taps are single-parity -> stride-2 reads,
// no 8-way conflicts), with reflected halos. 43.8 KB -> 3 blocks/CU.
// Tap addressing: E[u+4]=x[2u], O[u+4]=x[2u+1]; tap q of output mm reads
// index (2mm+9-q) in BOTH planes (u = 2mm+5-q), u range -4..259.
// =====================================================================
__global__ __launch_bounds__(256)
void k_level2b(const float* __restrict__ lo2, const float* __restrict__ hi2,
               float* __restrict__ out0, float* __restrict__ outh1) {
  const int bi = blockIdx.x;
  const int b  = bi >> 7;
  const int i  = bi & 127;
  const int tid = threadIdx.x;

  __shared__ float s_row[2][2][2][3][264]; // [lo/hi][hp][par][c][u+4], u=w>>1
  __shared__ float s_sub[3][2][768];       // [sb][hp][c*256 + m]

  // main body: 12 rows x 512 floats as float4, parity-split into E/O planes
  for (int k = 0; k < 6; ++k) {
    const int t4 = tid + (k << 8);         // 0..1535
    const int plane = t4 >> 7;             // 0..11
    const int f4i = t4 & 127;
    const int srcn = plane / 6;
    const int rem = plane - 6 * srcn;
    const int hp = rem / 3;
    const int cc = rem - 3 * hp;
    const float4 v = *((const float4*)((srcn ? hi2 : lo2)
                       + (((size_t)(b * 3 + cc) * 256) + (i << 1) + hp) * 512) + f4i);
    *(float2*)&s_row[srcn][hp][0][cc][2 * f4i + 4] = make_float2(v.x, v.z);
    *(float2*)&s_row[srcn][hp][1][cc][2 * f4i + 4] = make_float2(v.y, v.w);
  }
  // halos: BOTH parities need u = -4..-1 and 256..259 (8 slots each)
  if (tid < 192) {
    const int pl = tid >> 4;               // 0..11
    const int s  = tid & 15;
    const int srcn = pl / 6;
    const int rem = pl - 6 * srcn;
    const int hp = rem / 3;
    const int cc = rem - 3 * hp;
    const float* grow = (srcn ? hi2 : lo2)
                        + (((size_t)(b * 3 + cc) * 256) + (i << 1) + hp) * 512;
    const int par = s >> 3;
    const int s3  = s & 7;
    const int u   = (s3 < 4) ? (s3 - 4) : (252 + s3);
    s_row[srcn][hp][par][cc][u + 4] = grow[refl512(2 * u + par)];
  }
  __syncthreads();

  // W-coldfilt: 1536 outputs = (hp, par, c, mm); par wave-uniform
  for (int k = 0; k < 6; ++k) {
    const int it  = tid + (k << 8);
    const int mm  = it & 127;
    const int cc  = (it >> 7) % 3;
    const int par = (it / 384) & 1;
    const int hp  = it / 768;
    const float* ELo = &s_row[0][hp][0][cc][2 * mm + 9];   // tap q -> [-q]
    const float* OLo = &s_row[0][hp][1][cc][2 * mm + 9];
    const float* EHi = &s_row[1][hp][0][cc][2 * mm + 9];
    const float* OHi = &s_row[1][hp][1][cc][2 * mm + 9];
    float ll = 0.f, lh = 0.f, hl = 0.f, hh = 0.f;
    if (par == 0) {   // even m: lo-filter on E (off 10), hi-filter on O (off 11)
#pragma unroll
      for (int q = 0; q < 10; ++q) {
        if (dt::H0B[q] != 0.f) { ll += dt::H0B[q] * ELo[-q]; hl += dt::H0B[q] * EHi[-q]; }
        if (dt::H1A[q] != 0.f) { lh += dt::H1A[q] * OLo[-q]; hh += dt::H1A[q] * OHi[-q]; }
      }
    } else {          // odd m: lo-filter on O (off 11), hi-filter on E (off 10)
#pragma unroll
      for (int q = 0; q < 10; ++q) {
        if (dt::H0A[q] != 0.f) { ll += dt::H0A[q] * OLo[-q]; hl += dt::H0A[q] * OHi[-q]; }
        if (dt::H1B[q] != 0.f) { lh += dt::H1B[q] * ELo[-q]; hh += dt::H1B[q] * EHi[-q]; }
      }
    }
    const int m = (mm << 1) + par;
    out0[(((size_t)(b << 8) + (i << 1) + hp) * 256 + m) * 3 + cc] = ll;  // lolo2
    s_sub[0][hp][cc * 256 + m] = hl;   // hi_lo -> bands 0/5
    s_sub[1][hp][cc * 256 + m] = hh;   // hi_hi -> bands 1/4
    s_sub[2][hp][cc * 256 + m] = lh;   // lo_hi -> bands 2/3
  }
  __syncthreads();

  // q2c + pack out_h1 row (b,i): 128 j x 36, layout ri*18 + band*3 + c
  const size_t rowbase = ((size_t)(b << 7) + i) * 4608;
  for (int o = tid; o < 4608; o += 256) {
    const int cc   = o % 3;
    const int band = (o / 3) % 6;
    const int ri   = (o / 18) & 1;
    const int j    = o / 36;
    const int sb   = (band < 3) ? band : (5 - band);
    const bool sec = band >= 3;
    float v;
    if (ri == 0) {
      const float av = s_sub[sb][0][cc * 256 + 2 * j];
      const float dv = s_sub[sb][1][cc * 256 + 2 * j + 1];
      v = SQH * (sec ? (av + dv) : (av - dv));
    } else {
      const float bv = s_sub[sb][0][cc * 256 + 2 * j + 1];
      const float cv = s_sub[sb][1][cc * 256 + 2 * j];
      v = SQH * (sec ? (bv - cv) : (bv + cv));
    }
    outh1[rowbase + o] = v;
  }
}

// =====================================================================
extern "C" void kernel_launch(void* const* d_in, const int* in_sizes, int n_in,
                              void* d_out, int out_size, void* d_ws, size_t ws_size,
                              hipStream_t stream) {
  const float* x = (const float*)d_in[0];
  float* out = (float*)d_out;

  float* out0  = out;                    // 16*256*256*3
  float* outh0 = out + 3145728;          // 16*256*256*36
  float* outh1 = out + 40894464;         // 16*128*128*36

  float* lolo = (float*)d_ws;            // planar [b][c][512][512]
  float* lo2  = lolo + 12582912;         // planar [b][c][256][512]
  float* hi2  = lo2 + 6291456;           // planar [b][c][256][512]

  k_level1<<<dim3(16, 16, 16), 384, 0, stream>>>(x, lolo, outh0);
  k_coldfilt_h<<<6144, 256, 0, stream>>>(lolo, lo2, hi2);
  k_level2b<<<2048, 256, 0, stream>>>(lo2, hi2, out0, outh1);
}

// Round 7
// 104.210 us; speedup vs baseline: 1.7290x; 1.2491x over previous
//
#include <hip/hip_runtime.h>

#define SQH 0.70710678118654752440f

// ---------------- filter constants (fp32) ----------------
namespace dt {
// level-1 filter symmetric halves: unscaled (for lolo) and x sqrt(1/2) (subbands)
constexpr float H0Oh[3] = {-0.05f, 0.25f, 0.5f};
constexpr float H1Oh[4] = {-3.f/280.f, 15.f/280.f, 73.f/280.f, -170.f/280.f};
constexpr float H0Os[3] = {-0.05f*SQH, 0.25f*SQH, 0.5f*SQH};
constexpr float H1Os[4] = {(-3.f/280.f)*SQH, (15.f/280.f)*SQH,
                           (73.f/280.f)*SQH, (-170.f/280.f)*SQH};
// level-2 qshift filters
constexpr float H0B[10] = {0.03516384f, 0.f, -0.08832942f, 0.23389032f, 0.76027237f,
                           0.5875183f, 0.f, -0.11430184f, 0.f, 0.f};
constexpr float H0A[10] = {0.f, 0.f, -0.11430184f, 0.f, 0.5875183f,
                           0.76027237f, 0.23389032f, -0.08832942f, 0.f, 0.03516384f};
constexpr float H1A[10] = {0.03516384f, 0.f, -0.08832942f, -0.23389032f, 0.76027237f,
                           -0.5875183f, 0.f, 0.11430184f, 0.f, 0.f};
constexpr float H1B[10] = {0.f, 0.f, 0.11430184f, 0.f, -0.5875183f,
                           0.76027237f, -0.23389032f, -0.08832942f, 0.f, 0.03516384f};
}

// symmetric reflection for n=512 (single reflection; max overhang here is 10)
__device__ __forceinline__ int refl512(int i) {
  i = (i < 0) ? (-1 - i) : i;
  return (i > 511) ? (1023 - i) : i;
}

// =====================================================================
// Kernel 1: level-1. H-filter: each thread owns a column, loads its 17
// source rows FULLY UNROLLED into registers, then computes 11 filter
// rows. W-filter + q2c fused per 2x2 quad in registers; outh0 packed in
// LDS, flushed as float4. lolo written PLANAR [b][c][512][512].
// 384 threads; LDS 50.1 KB -> 3 blocks/CU. grid = (16,16,16).
// =====================================================================
__global__ __launch_bounds__(384)
void k_level1(const float* __restrict__ x, float* __restrict__ lolo,
              float* __restrict__ outh0) {
  const int b  = blockIdx.z;
  const int h0 = blockIdx.y << 5;
  const int w0 = blockIdx.x << 5;
  const int t  = threadIdx.x;

  __shared__ float s_lo[3 * 1320];   // [c]: plane 1320 = 33 rows x 40 (row 32 = pad)
  __shared__ float s_hi[3 * 1320];
  __shared__ float s_pack[4608];     // 8 out-rows x 576 (one half-tile of outh0)

  // ---------------- H phase: 17 loads up-front, then 11 rows ----------------
  {
    const int q = t & 127;           // column id: cw*3+c, valid < 114
    const int g = t >> 7;            // 0..2 -> row blocks 0-10, 11-21, 22-32(pad)
    if (q < 114) {
      const int cw = q / 3;
      const int c  = q - 3 * cw;
      const int gw = refl512(w0 - 3 + cw);
      const float* xc = x + (size_t)b * 786432 + gw * 3 + c;
      const int rbeg = g * 11;
      float v[17];
#pragma unroll
      for (int rr = 0; rr < 17; ++rr)
        v[rr] = xc[refl512(h0 + rbeg - 3 + rr) * 1536];
      float* plo = s_lo + c * 1320 + rbeg * 40 + cw;
      float* phi = s_hi + c * 1320 + rbeg * 40 + cw;
#pragma unroll
      for (int rr = 0; rr < 11; ++rr) {   // g=2: row 32 lands in pad row, unread
        plo[rr * 40] = dt::H0Oh[0]*(v[rr+1]+v[rr+5]) + dt::H0Oh[1]*(v[rr+2]+v[rr+4])
                     + dt::H0Oh[2]*v[rr+3];
        phi[rr * 40] = dt::H1Oh[0]*(v[rr]+v[rr+6]) + dt::H1Oh[1]*(v[rr+1]+v[rr+5])
                     + dt::H1Oh[2]*(v[rr+2]+v[rr+4]) + dt::H1Oh[3]*v[rr+3];
      }
    }
  }

  // quad decode (bijection t -> rp0*48 + jq*3 + c)
  const int c   = t % 3;
  const int jq  = (t / 3) & 15;
  const int rp0 = t / 48;                 // 0..7
  const int lobase = c * 1320 + 2 * jq;

  for (int half = 0; half < 2; ++half) {
    __syncthreads();   // H-writes visible (half 0) / pack flushed (half 1)

    // ------------- quad phase: 2x2 spatial, one channel -------------
    const int rp = rp0 + (half << 3);     // global row-pair 0..15
    const int r0 = rp << 1;
    float L0[10], L1[10], G0[10], G1[10];
    {
      const float2* a = (const float2*)(s_lo + lobase + r0 * 40);
      const float2* bq = (const float2*)(s_lo + lobase + r0 * 40 + 40);
      const float2* d = (const float2*)(s_hi + lobase + r0 * 40);
      const float2* e = (const float2*)(s_hi + lobase + r0 * 40 + 40);
#pragma unroll
      for (int u = 0; u < 5; ++u) {
        float2 va = a[u];  L0[2*u] = va.x; L0[2*u+1] = va.y;
        float2 vb = bq[u]; L1[2*u] = vb.x; L1[2*u+1] = vb.y;
        float2 vd = d[u];  G0[2*u] = vd.x; G0[2*u+1] = vd.y;
        float2 ve = e[u];  G1[2*u] = ve.x; G1[2*u+1] = ve.y;
      }
    }
    const float ll00 = dt::H0Oh[0]*(L0[1]+L0[5]) + dt::H0Oh[1]*(L0[2]+L0[4]) + dt::H0Oh[2]*L0[3];
    const float ll01 = dt::H0Oh[0]*(L0[2]+L0[6]) + dt::H0Oh[1]*(L0[3]+L0[5]) + dt::H0Oh[2]*L0[4];
    const float ll10 = dt::H0Oh[0]*(L1[1]+L1[5]) + dt::H0Oh[1]*(L1[2]+L1[4]) + dt::H0Oh[2]*L1[3];
    const float ll11 = dt::H0Oh[0]*(L1[2]+L1[6]) + dt::H0Oh[1]*(L1[3]+L1[5]) + dt::H0Oh[2]*L1[4];

    const float lh00 = dt::H1Os[0]*(L0[0]+L0[6]) + dt::H1Os[1]*(L0[1]+L0[5]) + dt::H1Os[2]*(L0[2]+L0[4]) + dt::H1Os[3]*L0[3];
    const float lh01 = dt::H1Os[0]*(L0[1]+L0[7]) + dt::H1Os[1]*(L0[2]+L0[6]) + dt::H1Os[2]*(L0[3]+L0[5]) + dt::H1Os[3]*L0[4];
    const float lh10 = dt::H1Os[0]*(L1[0]+L1[6]) + dt::H1Os[1]*(L1[1]+L1[5]) + dt::H1Os[2]*(L1[2]+L1[4]) + dt::H1Os[3]*L1[3];
    const float lh11 = dt::H1Os[0]*(L1[1]+L1[7]) + dt::H1Os[1]*(L1[2]+L1[6]) + dt::H1Os[2]*(L1[3]+L1[5]) + dt::H1Os[3]*L1[4];

    const float hl00 = dt::H0Os[0]*(G0[1]+G0[5]) + dt::H0Os[1]*(G0[2]+G0[4]) + dt::H0Os[2]*G0[3];
    const float hl01 = dt::H0Os[0]*(G0[2]+G0[6]) + dt::H0Os[1]*(G0[3]+G0[5]) + dt::H0Os[2]*G0[4];
    const float hl10 = dt::H0Os[0]*(G1[1]+G1[5]) + dt::H0Os[1]*(G1[2]+G1[4]) + dt::H0Os[2]*G1[3];
    const float hl11 = dt::H0Os[0]*(G1[2]+G1[6]) + dt::H0Os[1]*(G1[3]+G1[5]) + dt::H0Os[2]*G1[4];

    const float hh00 = dt::H1Os[0]*(G0[0]+G0[6]) + dt::H1Os[1]*(G0[1]+G0[5]) + dt::H1Os[2]*(G0[2]+G0[4]) + dt::H1Os[3]*G0[3];
    const float hh01 = dt::H1Os[0]*(G0[1]+G0[7]) + dt::H1Os[1]*(G0[2]+G0[6]) + dt::H1Os[2]*(G0[3]+G0[5]) + dt::H1Os[3]*G0[4];
    const float hh10 = dt::H1Os[0]*(G1[0]+G1[6]) + dt::H1Os[1]*(G1[1]+G1[5]) + dt::H1Os[2]*(G1[2]+G1[4]) + dt::H1Os[3]*G1[3];
    const float hh11 = dt::H1Os[0]*(G1[1]+G1[7]) + dt::H1Os[1]*(G1[2]+G1[6]) + dt::H1Os[2]*(G1[3]+G1[5]) + dt::H1Os[3]*G1[4];

    // lolo planar store (float2 per row)
    {
      float* lp = lolo + (((size_t)(b * 3 + c) * 512) + (h0 + r0)) * 512 + w0 + 2 * jq;
      *(float2*)lp = make_float2(ll00, ll01);
      *(float2*)(lp + 512) = make_float2(ll10, ll11);
    }

    // q2c in registers
    {
      float* pk = s_pack + rp0 * 576 + jq * 36 + c * 6;
      pk[0]  = hl00 - hl11;  pk[18] = hl01 + hl10;   // band 0
      pk[5]  = hl00 + hl11;  pk[23] = hl01 - hl10;   // band 5
      pk[1]  = hh00 - hh11;  pk[19] = hh01 + hh10;   // band 1
      pk[4]  = hh00 + hh11;  pk[22] = hh01 - hh10;   // band 4
      pk[2]  = lh00 - lh11;  pk[20] = lh01 + lh10;   // band 2
      pk[3]  = lh00 + lh11;  pk[21] = lh01 - lh10;   // band 3
    }
    __syncthreads();

    // ------------- flush: 8 rows x 576 floats, float4 coalesced -------------
    {
      const int gi0 = (h0 >> 1) + (half << 3);
      float4* gout = (float4*)(outh0 + ((((size_t)b << 8) + gi0) << 8) * 36
                               + (size_t)(w0 >> 1) * 36);
      const float4* sp = (const float4*)s_pack;
#pragma unroll
      for (int k = 0; k < 3; ++k) {
        const int item = t + k * 384;      // 0..1151
        const int row  = item / 144;
        const int f4   = item - row * 144;
        gout[(size_t)row * 2304 + f4] = sp[item];
      }
    }
  }
}

// =====================================================================
// Kernel 2 (FUSED): both level-2 coldfilts. Per block: one batch b,
// 4 output rows m in [4*jb, 4*jb+4). Phase 1: H-coldfilt of lolo into
// LDS s_mid (parity-split cols, halo-extended, all 3 channels).
// Phase 2: W-coldfilt + register q2c per 2x2 quad; writes lolo2 (out0)
// and out_h1 directly. Eliminates the lo2/hi2 HBM round trip.
// s_mid[src][c][mi][par][266]: E[u+4]=col 2u, O[u+4]=col 2u+1,
// u in [-4,259] (cols -8..519, reflected). 51 KB -> 3 blocks/CU.
// Tap rule (from verified k2a/k2b): output index m=2n+parm:
//   parm=0: lo=H0B rows/cols ref(4n+10-2q); hi=H1A ref(4n+11-2q)
//   parm=1: lo=H0A ref(4n+11-2q);           hi=H1B ref(4n+10-2q)
// In parity-split storage both reduce to window arrayidx 2j+9-q.
// grid = 16*64 = 1024 blocks, 256 threads.
// =====================================================================
#define SM(s, c, r, p) (((((s)*3 + (c))*4 + (r))*2 + (p)) * 266)

__global__ __launch_bounds__(256)
void k_level2(const float* __restrict__ lolo, float* __restrict__ out0,
              float* __restrict__ outh1) {
  const int bi = blockIdx.x;
  const int b  = bi >> 6;
  const int jb = bi & 63;
  const int t  = threadIdx.x;
  const int n0 = jb << 1;
  const int m0 = jb << 2;

  __shared__ float s_mid[12768];   // 2*3*4*2*266

  // ---- phase 1 main: 1536 items = c(3) x mi(4) x f4group(128) ----
  for (int k = 0; k < 6; ++k) {
    const int idx = t + (k << 8);
    const int g  = idx & 127;
    const int mi = (idx >> 7) & 3;         // wave-uniform
    const int cc = idx >> 9;               // wave-uniform
    const int n  = n0 + (mi >> 1);
    const float4* sp = (const float4*)(lolo + (size_t)(b*3+cc) * 262144) + g;
    float4 alo = make_float4(0.f,0.f,0.f,0.f);
    float4 ahi = make_float4(0.f,0.f,0.f,0.f);
#define ACC4(acc, h, row) { const float4 v = sp[(size_t)(row)*128];     \
    acc.x += (h)*v.x; acc.y += (h)*v.y; acc.z += (h)*v.z; acc.w += (h)*v.w; }
    if ((mi & 1) == 0) {
#pragma unroll
      for (int q = 0; q < 10; ++q) {
        if (dt::H0B[q] != 0.f) ACC4(alo, dt::H0B[q], refl512(4*n + 10 - 2*q));
        if (dt::H1A[q] != 0.f) ACC4(ahi, dt::H1A[q], refl512(4*n + 11 - 2*q));
      }
    } else {
#pragma unroll
      for (int q = 0; q < 10; ++q) {
        if (dt::H0A[q] != 0.f) ACC4(alo, dt::H0A[q], refl512(4*n + 11 - 2*q));
        if (dt::H1B[q] != 0.f) ACC4(ahi, dt::H1B[q], refl512(4*n + 10 - 2*q));
      }
    }
#undef ACC4
    // cols 4g..4g+3 -> E[2g+4],E[2g+5] = (x,z); O[2g+4],O[2g+5] = (y,w)
    *(float2*)&s_mid[SM(0,cc,mi,0) + 2*g + 4] = make_float2(alo.x, alo.z);
    *(float2*)&s_mid[SM(0,cc,mi,1) + 2*g + 4] = make_float2(alo.y, alo.w);
    *(float2*)&s_mid[SM(1,cc,mi,0) + 2*g + 4] = make_float2(ahi.x, ahi.z);
    *(float2*)&s_mid[SM(1,cc,mi,1) + 2*g + 4] = make_float2(ahi.y, ahi.w);
  }

  // ---- phase 1 halo: cols -8..-1, 512..519 (scalar, reflected) ----
  {
    const int mi  = t >> 6;                // wave-uniform
    const int rem = t & 63;
    if (rem < 48) {
      const int cc = rem >> 4;
      const int hc = rem & 15;
      const int w  = (hc < 8) ? (hc - 8) : (504 + hc);
      const int u  = w >> 1;               // arithmetic shift: -7>>1 = -4
      const int par = w & 1;
      const int wc = refl512(w);
      const int n  = n0 + (mi >> 1);
      const float* sp = lolo + (size_t)(b*3+cc) * 262144 + wc;
      float alo = 0.f, ahi = 0.f;
      if ((mi & 1) == 0) {
#pragma unroll
        for (int q = 0; q < 10; ++q) {
          if (dt::H0B[q] != 0.f) alo += dt::H0B[q] * sp[(size_t)refl512(4*n+10-2*q)*512];
          if (dt::H1A[q] != 0.f) ahi += dt::H1A[q] * sp[(size_t)refl512(4*n+11-2*q)*512];
        }
      } else {
#pragma unroll
        for (int q = 0; q < 10; ++q) {
          if (dt::H0A[q] != 0.f) alo += dt::H0A[q] * sp[(size_t)refl512(4*n+11-2*q)*512];
          if (dt::H1B[q] != 0.f) ahi += dt::H1B[q] * sp[(size_t)refl512(4*n+10-2*q)*512];
        }
      }
      s_mid[SM(0,cc,mi,par) + u + 4] = alo;
      s_mid[SM(1,cc,mi,par) + u + 4] = ahi;
    }
  }
  __syncthreads();

  // ---- phase 2: 768 quads = rp(2) x j(128) x c(3), c fastest ----
  for (int k = 0; k < 3; ++k) {
    const int idx = t + (k << 8);
    const int cc = idx % 3;
    const int jj = (idx / 3) & 127;
    const int rp = idx / 384;              // wave-uniform
    const int base0 = 2 * jj;              // window start (array idx, even)

    float q_hl[2][2], q_hh[2][2], q_lh[2][2];   // [r][col-par]
#pragma unroll
    for (int r = 0; r < 2; ++r) {
      const int mi = (rp << 1) + r;
      float el[10], ol[10], eh[10], oh[10];
#pragma unroll
      for (int u = 0; u < 5; ++u) {
        const float2 v0 = *(const float2*)&s_mid[SM(0,cc,mi,0) + base0 + 2*u];
        el[2*u] = v0.x; el[2*u+1] = v0.y;
        const float2 v1 = *(const float2*)&s_mid[SM(0,cc,mi,1) + base0 + 2*u];
        ol[2*u] = v1.x; ol[2*u+1] = v1.y;
        const float2 v2 = *(const float2*)&s_mid[SM(1,cc,mi,0) + base0 + 2*u];
        eh[2*u] = v2.x; eh[2*u+1] = v2.y;
        const float2 v3 = *(const float2*)&s_mid[SM(1,cc,mi,1) + base0 + 2*u];
        oh[2*u] = v3.x; oh[2*u+1] = v3.y;
      }
      float ll_e = 0.f, ll_o = 0.f, hl_e = 0.f, hl_o = 0.f;
      float lh_e = 0.f, lh_o = 0.f, hh_e = 0.f, hh_o = 0.f;
#pragma unroll
      for (int q = 0; q < 10; ++q) {       // tap q reads window[9-q]
        if (dt::H0B[q] != 0.f) { ll_e += dt::H0B[q]*el[9-q]; hl_e += dt::H0B[q]*eh[9-q]; }
        if (dt::H0A[q] != 0.f) { ll_o += dt::H0A[q]*ol[9-q]; hl_o += dt::H0A[q]*oh[9-q]; }
        if (dt::H1A[q] != 0.f) { lh_e += dt::H1A[q]*ol[9-q]; hh_e += dt::H1A[q]*oh[9-q]; }
        if (dt::H1B[q] != 0.f) { lh_o += dt::H1B[q]*el[9-q]; hh_o += dt::H1B[q]*eh[9-q]; }
      }
      // lolo2 -> out0 (interleaved [b][h][w][c])
      float* o0 = out0 + (((size_t)(b << 8) + (m0 + mi)) * 256 + 2*jj) * 3 + cc;
      o0[0] = ll_e; o0[3] = ll_o;
      q_hl[r][0] = hl_e; q_hl[r][1] = hl_o;
      q_hh[r][0] = hh_e; q_hh[r][1] = hh_o;
      q_lh[r][0] = lh_e; q_lh[r][1] = lh_o;
    }
    // q2c: a=(r0,e) b=(r0,o) c=(r1,e) d=(r1,o); comp = ri*18 + band*3 + cc
    const int iout = (jb << 1) + rp;
    float* oh1 = outh1 + (((size_t)(b << 7) + iout) * 128 + jj) * 36 + cc;
    oh1[0]  = SQH * (q_hl[0][0] - q_hl[1][1]);   // band0 re
    oh1[18] = SQH * (q_hl[0][1] + q_hl[1][0]);   // band0 im
    oh1[15] = SQH * (q_hl[0][0] + q_hl[1][1]);   // band5 re
    oh1[33] = SQH * (q_hl[0][1] - q_hl[1][0]);   // band5 im
    oh1[3]  = SQH * (q_hh[0][0] - q_hh[1][1]);   // band1 re
    oh1[21] = SQH * (q_hh[0][1] + q_hh[1][0]);   // band1 im
    oh1[12] = SQH * (q_hh[0][0] + q_hh[1][1]);   // band4 re
    oh1[30] = SQH * (q_hh[0][1] - q_hh[1][0]);   // band4 im
    oh1[6]  = SQH * (q_lh[0][0] - q_lh[1][1]);   // band2 re
    oh1[24] = SQH * (q_lh[0][1] + q_lh[1][0]);   // band2 im
    oh1[9]  = SQH * (q_lh[0][0] + q_lh[1][1]);   // band3 re
    oh1[27] = SQH * (q_lh[0][1] - q_lh[1][0]);   // band3 im
  }
}

// =====================================================================
extern "C" void kernel_launch(void* const* d_in, const int* in_sizes, int n_in,
                              void* d_out, int out_size, void* d_ws, size_t ws_size,
                              hipStream_t stream) {
  const float* x = (const float*)d_in[0];
  float* out = (float*)d_out;

  float* out0  = out;                    // 16*256*256*3
  float* outh0 = out + 3145728;          // 16*256*256*36
  float* outh1 = out + 40894464;         // 16*128*128*36

  float* lolo = (float*)d_ws;            // planar [b][c][512][512], 48 MB

  k_level1<<<dim3(16, 16, 16), 384, 0, stream>>>(x, lolo, outh0);
  k_level2<<<1024, 256, 0, stream>>>(lolo, out0, outh1);
}